// Round 7
// baseline (1578.960 us; speedup 1.0000x reference)
//
#include <hip/hip_runtime.h>

// PointNet++ SA module: FPS -> ball query -> group -> SharedMLP(3) -> maxpool
// B=8, N=8192, C_IN=64, M=1024, K=64, RADIUS=0.2, MLP=[64,64,128]

#define B_ 8
#define N_ 8192
#define M_ 1024
#define K_ 64
#define FTW 68  // 3 xyz + 64 feat + 1 pad (row = 272B, 16B aligned)

// ---------------------------------------------------------------------------
// DPP reduction helpers (pure VALU, no LDS pipe). Standard CDNA idiom:
// levels xor1/xor2/half_mirror/mirror are complete permutations (no
// zero-fill); bcast15/bcast31 zero-fill non-receiving lanes but the chain
// toward lane 63 reads only valid sources -> lane 63 holds the wave result.
// ---------------------------------------------------------------------------
template <int CTRL>
__device__ __forceinline__ float dpp_fmax(float v) {
  int o = __builtin_amdgcn_update_dpp(0, __float_as_int(v), CTRL, 0xF, 0xF, true);
  return fmaxf(v, __int_as_float(o));
}
// Wave max (values >= 0); valid in lane 63 only.
__device__ __forceinline__ float wave_fmax63(float v) {
  v = dpp_fmax<0xB1>(v);   // quad_perm xor1
  v = dpp_fmax<0x4E>(v);   // quad_perm xor2
  v = dpp_fmax<0x141>(v);  // row_half_mirror
  v = dpp_fmax<0x140>(v);  // row_mirror -> row max in all 16 lanes
  v = dpp_fmax<0x142>(v);  // row_bcast15
  v = dpp_fmax<0x143>(v);  // row_bcast31 -> lane 63 = wave max
  return v;
}
template <int CTRL>
__device__ __forceinline__ unsigned int dpp_umin(unsigned int v) {
  int o = __builtin_amdgcn_update_dpp(0, (int)v, CTRL, 0xF, 0xF, true);
  unsigned int ov = (unsigned int)o;
  return ov < v ? ov : v;
}
// Wave min of u32; valid in lane 63 only (zero-filled lanes corrupt lanes
// 0..47 at bcast levels but lane 63's sources are valid).
__device__ __forceinline__ unsigned int wave_umin63(unsigned int v) {
  v = dpp_umin<0xB1>(v);
  v = dpp_umin<0x4E>(v);
  v = dpp_umin<0x141>(v);
  v = dpp_umin<0x140>(v);
  v = dpp_umin<0x142>(v);
  v = dpp_umin<0x143>(v);
  return v;
}

// ---------------------------------------------------------------------------
// Kernel 1 (fused): blocks 0..7 = exact FPS (one CU per batch);
//                   blocks 8..  = build ft[b][n][0..67] = {x,y,z,f0..f63,0}.
// FPS: 256 threads (4 waves, 1/SIMD) x 32 points, scalar exact arithmetic.
// Value-first argmax, index deferred to the winning wave only:
//   dist loop (10 ops/pt, bestv via fmax) -> f32 DPP wave max -> lane63
//   writes candv[wid]; barrier1; all lanes: one ds_read_b128 -> block max
//   (SGPR); ONLY the wave whose max == block max (scalar branch) runs the
//   32-compare equality scan (earliest local j), u32 min DPP reduce, and one
//   LDS atomicMin into the parity slot; barrier2; read gi + pts4[gi].
// Tie-break: exact-equality scan + global index min == first-occurrence
// argmax. Distances: unfused f32 sub/mul/add in x,y,z order (bit-exact).
// Slot init for iter i+1 sits between barrier1(i) and barrier2(i):
//   read(slot,i) < b1(i+1)... wait-free proof in session notes: init(slot
//   1-q during i) < b2(i) < b1(i+1) < atomicMin(slot 1-q, i+1) and all
//   reads of slot 1-q from i-1 precede b1(i). No unordered access pairs.
// ---------------------------------------------------------------------------
__global__ __launch_bounds__(256) void fps_ft_kernel(const float* __restrict__ xyz,
                                                     const float* __restrict__ feat,
                                                     float* __restrict__ ft,
                                                     float* __restrict__ nxyz) {
#pragma clang fp contract(off)
  if (blockIdx.x >= 8) {
    // ---- build_ft path (no LDS use, no barriers) ----
    const int nb = gridDim.x - 8;
    const int total = B_ * N_ * FTW;
    for (int idx = (blockIdx.x - 8) * 256 + threadIdx.x; idx < total; idx += nb * 256) {
      int c = idx % FTW;
      int bn = idx / FTW;
      int n = bn & (N_ - 1);
      int b = bn >> 13;
      float v;
      if (c < 3) v = xyz[(b * 3 + c) * N_ + n];
      else if (c < 67) v = feat[(b * 64 + (c - 3)) * N_ + n];
      else v = 0.f;
      ft[idx] = v;
    }
    return;
  }

  // ---- FPS path ----
  __shared__ float4 pts4[N_];        // 128 KB point table (w unused)
  __shared__ float candv[4];         // wave maxes (single-buffered: b1/b2 fence it)
  __shared__ unsigned int sidx[2];   // parity-buffered winning index (atomicMin)
  __shared__ int scidx[M_];
  const int b = blockIdx.x;
  const int t = threadIdx.x;
  const int lane = t & 63;
  const int wid = t >> 6;  // 0..3
  const float* xb = xyz + b * 3 * N_;

  for (int n = t; n < N_; n += 256) {
    pts4[n] = make_float4(xb[n], xb[N_ + n], xb[2 * N_ + n], 0.f);
  }

  const int base = t * 32;
  float px[32], py[32], pz[32], mind[32];
#pragma unroll
  for (int j = 0; j < 32; ++j) {
    px[j] = xb[base + j];
    py[j] = xb[N_ + base + j];
    pz[j] = xb[2 * N_ + base + j];
    mind[j] = 1e10f;
  }
  float xl = xb[0], yl = xb[N_], zl = xb[2 * N_];
  if (t == 0) {
    scidx[0] = 0;
    sidx[0] = 0xFFFFFFFFu;
    sidx[1] = 0xFFFFFFFFu;
  }
  __syncthreads();

  for (int i = 1; i < M_; ++i) {
    const int q = i & 1;
    float bestv = -1.f;
#pragma unroll
    for (int j = 0; j < 32; ++j) {
      float dx = __fsub_rn(px[j], xl);
      float dy = __fsub_rn(py[j], yl);
      float dz = __fsub_rn(pz[j], zl);
      float d = __fadd_rn(__fadd_rn(__fmul_rn(dx, dx), __fmul_rn(dy, dy)), __fmul_rn(dz, dz));
      float md = fminf(mind[j], d);
      mind[j] = md;
      bestv = fmaxf(bestv, md);  // value only — index deferred
    }
    float wv = wave_fmax63(bestv);
    const int wvbits = __builtin_amdgcn_readlane(__float_as_int(wv), 63);  // SGPR
    if (lane == 63) candv[wid] = wv;
    __syncthreads();  // barrier 1
    const float4 cv = *(const float4*)candv;  // broadcast ds_read_b128
    const float bmax = fmaxf(fmaxf(cv.x, cv.y), fmaxf(cv.z, cv.w));
    const int bmaxbits = __builtin_amdgcn_readfirstlane(__float_as_int(bmax));
    if (t == 0) sidx[1 - q] = 0xFFFFFFFFu;  // init NEXT iter's slot (between b1,b2)
    if (wvbits == bmaxbits) {  // scalar compare -> wave-uniform branch (~1 of 4 waves)
      int myj = 64;
#pragma unroll
      for (int j = 31; j >= 0; --j)  // descending overwrite -> smallest j kept
        if (__float_as_int(mind[j]) == bmaxbits) myj = j;
      unsigned int myidx = (myj < 64) ? (unsigned int)(base + myj) : 0xFFFFFFFFu;
      unsigned int mi = wave_umin63(myidx);
      if (lane == 63) atomicMin(&sidx[q], mi);
    }
    __syncthreads();  // barrier 2
    const unsigned int gi = sidx[q];
    if (t == 0) scidx[i] = (int)gi;
    float4 cc = pts4[gi];  // broadcast ds_read_b128, conflict-free
    xl = cc.x; yl = cc.y; zl = cc.z;
  }
  __syncthreads();
  for (int qi = t; qi < M_; qi += 256) {
    int ci = scidx[qi];
    float4 c = pts4[ci];
    nxyz[b * 3 * M_ + qi] = c.x;
    nxyz[b * 3 * M_ + M_ + qi] = c.y;
    nxyz[b * 3 * M_ + 2 * M_ + qi] = c.z;
  }
}

// ---------------------------------------------------------------------------
// Kernel 2: ball query — one wave per centroid, ordered first-K within radius.
// Replicates the reference's expanded-form distance exactly (unfused f32).
// Threshold 0.04f == f32(0.2*0.2 computed in python f64).
// ---------------------------------------------------------------------------
__global__ __launch_bounds__(256) void ballq_kernel(const float* __restrict__ xyz,
                                                    const float* __restrict__ nxyz,
                                                    int* __restrict__ nidx) {
  const int lane = threadIdx.x & 63;
  const int g = blockIdx.x * 4 + (threadIdx.x >> 6);  // 0..8191 centroid id
  const int b = g >> 10;
  const int m = g & (M_ - 1);
  const float* xb = xyz + b * 3 * N_;
  const float cx = nxyz[b * 3 * M_ + m];
  const float cy = nxyz[b * 3 * M_ + M_ + m];
  const float cz = nxyz[b * 3 * M_ + 2 * M_ + m];
  const float nc = __fadd_rn(__fadd_rn(__fmul_rn(cx, cx), __fmul_rn(cy, cy)), __fmul_rn(cz, cz));
  int cnt = 0;
  int first = 0;
  int* slot = nidx + (g << 6);
  for (int basei = 0; basei < N_ && cnt < K_; basei += 64) {
    const int n = basei + lane;
    float p_x = xb[n], p_y = xb[N_ + n], p_z = xb[2 * N_ + n];
    float pn = __fadd_rn(__fadd_rn(__fmul_rn(p_x, p_x), __fmul_rn(p_y, p_y)), __fmul_rn(p_z, p_z));
    float dt = __fadd_rn(__fadd_rn(__fmul_rn(cx, p_x), __fmul_rn(cy, p_y)), __fmul_rn(cz, p_z));
    float d2 = __fsub_rn(__fadd_rn(nc, pn), __fmul_rn(2.f, dt));
    bool inr = d2 < 0.04f;
    unsigned long long mk = __ballot(inr);
    if (cnt == 0 && mk != 0ull) first = basei + (__ffsll((long long)mk) - 1);
    int pos = cnt + (int)__popcll(mk & ((1ull << lane) - 1ull));
    if (inr && pos < K_) slot[pos] = n;
    cnt += (int)__popcll(mk);
  }
  if (cnt > K_) cnt = K_;
  if (lane >= cnt) slot[lane] = first;  // pad with first hit (0 if none)
}

// ---------------------------------------------------------------------------
// Kernel 3: fused group + SharedMLP(67->64->64->128) + max over K.
// One wave per (b,m); lane = neighbor column. Rolled o-loops with 4-way
// output unroll (4 independent fmaf chains); LDS column (stride 65,
// conflict-free) bridges dynamic-o stores -> static-ci reloads. Max over
// the 64 neighbor lanes via 6-level DPP v_max chain (pure VALU) + readlane.
// Per-output FMA order identical to reference accumulation order.
// ---------------------------------------------------------------------------
template <bool USE_FT>
__global__ __launch_bounds__(64) void mlp_kernel(
    const float* __restrict__ ft, const float* __restrict__ xyz, const float* __restrict__ feat,
    const int* __restrict__ nidx, const float* __restrict__ nxyz,
    const float* __restrict__ w0, const float* __restrict__ s0, const float* __restrict__ b0,
    const float* __restrict__ w1, const float* __restrict__ s1, const float* __restrict__ b1,
    const float* __restrict__ w2, const float* __restrict__ s2, const float* __restrict__ b2,
    float* __restrict__ out2) {
  __shared__ float ylds[64 * 65];
  const int g = blockIdx.x;
  const int b = g >> 10;
  const int m = g & (M_ - 1);
  const int lane = threadIdx.x;
  const int n = nidx[(g << 6) + lane];
  const float cx = nxyz[b * 3 * M_ + m];
  const float cy = nxyz[b * 3 * M_ + M_ + m];
  const float cz = nxyz[b * 3 * M_ + 2 * M_ + m];

  float x0[67];
  if (USE_FT) {
    const float4* row = (const float4*)(ft + (size_t)((b << 13) + n) * FTW);
    float f[FTW];
#pragma unroll
    for (int q = 0; q < 17; ++q) {
      float4 v = row[q];
      f[q * 4 + 0] = v.x; f[q * 4 + 1] = v.y; f[q * 4 + 2] = v.z; f[q * 4 + 3] = v.w;
    }
    x0[0] = f[0] - cx; x0[1] = f[1] - cy; x0[2] = f[2] - cz;
#pragma unroll
    for (int c = 3; c < 67; ++c) x0[c] = f[c];
  } else {
    const float* xb = xyz + b * 3 * N_;
    x0[0] = xb[n] - cx; x0[1] = xb[N_ + n] - cy; x0[2] = xb[2 * N_ + n] - cz;
#pragma unroll
    for (int c = 0; c < 64; ++c) x0[3 + c] = feat[((b << 6) + c) * N_ + n];
  }

  // Layer 0: 67 -> 64 (4 outputs in flight)
  for (int o = 0; o < 64; o += 4) {
    const float* wr = w0 + o * 67;
    float a0 = 0.f, a1 = 0.f, a2 = 0.f, a3 = 0.f;
#pragma unroll
    for (int ci = 0; ci < 67; ++ci) {
      float xvv = x0[ci];
      a0 = fmaf(wr[ci], xvv, a0);
      a1 = fmaf(wr[67 + ci], xvv, a1);
      a2 = fmaf(wr[134 + ci], xvv, a2);
      a3 = fmaf(wr[201 + ci], xvv, a3);
    }
    ylds[lane * 65 + o + 0] = fmaxf(fmaf(a0, s0[o + 0], b0[o + 0]), 0.f);
    ylds[lane * 65 + o + 1] = fmaxf(fmaf(a1, s0[o + 1], b0[o + 1]), 0.f);
    ylds[lane * 65 + o + 2] = fmaxf(fmaf(a2, s0[o + 2], b0[o + 2]), 0.f);
    ylds[lane * 65 + o + 3] = fmaxf(fmaf(a3, s0[o + 3], b0[o + 3]), 0.f);
  }
  float x1[64];
#pragma unroll
  for (int c = 0; c < 64; ++c) x1[c] = ylds[lane * 65 + c];

  // Layer 1: 64 -> 64 (4 outputs in flight)
  for (int o = 0; o < 64; o += 4) {
    const float* wr = w1 + o * 64;
    float a0 = 0.f, a1 = 0.f, a2 = 0.f, a3 = 0.f;
#pragma unroll
    for (int ci = 0; ci < 64; ++ci) {
      float xvv = x1[ci];
      a0 = fmaf(wr[ci], xvv, a0);
      a1 = fmaf(wr[64 + ci], xvv, a1);
      a2 = fmaf(wr[128 + ci], xvv, a2);
      a3 = fmaf(wr[192 + ci], xvv, a3);
    }
    ylds[lane * 65 + o + 0] = fmaxf(fmaf(a0, s1[o + 0], b1[o + 0]), 0.f);
    ylds[lane * 65 + o + 1] = fmaxf(fmaf(a1, s1[o + 1], b1[o + 1]), 0.f);
    ylds[lane * 65 + o + 2] = fmaxf(fmaf(a2, s1[o + 2], b1[o + 2]), 0.f);
    ylds[lane * 65 + o + 3] = fmaxf(fmaf(a3, s1[o + 3], b1[o + 3]), 0.f);
  }
  float x2[64];
#pragma unroll
  for (int c = 0; c < 64; ++c) x2[c] = ylds[lane * 65 + c];

  // Layer 2: 64 -> 128, fused max over K (4 outputs in flight, DPP reduce)
  float* outbm = out2 + (size_t)(b * 128) * M_ + m;
  for (int o = 0; o < 128; o += 4) {
    const float* wr = w2 + o * 64;
    float a0 = 0.f, a1 = 0.f, a2 = 0.f, a3 = 0.f;
#pragma unroll
    for (int ci = 0; ci < 64; ++ci) {
      float xvv = x2[ci];
      a0 = fmaf(wr[ci], xvv, a0);
      a1 = fmaf(wr[64 + ci], xvv, a1);
      a2 = fmaf(wr[128 + ci], xvv, a2);
      a3 = fmaf(wr[192 + ci], xvv, a3);
    }
    float v0 = fmaxf(fmaf(a0, s2[o + 0], b2[o + 0]), 0.f);
    float v1 = fmaxf(fmaf(a1, s2[o + 1], b2[o + 1]), 0.f);
    float v2 = fmaxf(fmaf(a2, s2[o + 2], b2[o + 2]), 0.f);
    float v3 = fmaxf(fmaf(a3, s2[o + 3], b2[o + 3]), 0.f);
    v0 = wave_fmax63(v0);
    v1 = wave_fmax63(v1);
    v2 = wave_fmax63(v2);
    v3 = wave_fmax63(v3);
    float g0 = __int_as_float(__builtin_amdgcn_readlane(__float_as_int(v0), 63));
    float g1 = __int_as_float(__builtin_amdgcn_readlane(__float_as_int(v1), 63));
    float g2 = __int_as_float(__builtin_amdgcn_readlane(__float_as_int(v2), 63));
    float g3 = __int_as_float(__builtin_amdgcn_readlane(__float_as_int(v3), 63));
    if (lane == ((o + 0) & 63)) outbm[(o + 0) * M_] = g0;
    if (lane == ((o + 1) & 63)) outbm[(o + 1) * M_] = g1;
    if (lane == ((o + 2) & 63)) outbm[(o + 2) * M_] = g2;
    if (lane == ((o + 3) & 63)) outbm[(o + 3) * M_] = g3;
  }
}

// ---------------------------------------------------------------------------
extern "C" void kernel_launch(void* const* d_in, const int* in_sizes, int n_in,
                              void* d_out, int out_size, void* d_ws, size_t ws_size,
                              hipStream_t stream) {
  const float* xyz = (const float*)d_in[0];
  const float* feat = (const float*)d_in[1];
  const float* w0 = (const float*)d_in[2];
  const float* s0 = (const float*)d_in[3];
  const float* b0 = (const float*)d_in[4];
  const float* w1 = (const float*)d_in[5];
  const float* s1 = (const float*)d_in[6];
  const float* b1 = (const float*)d_in[7];
  const float* w2 = (const float*)d_in[8];
  const float* s2 = (const float*)d_in[9];
  const float* b2 = (const float*)d_in[10];

  float* nxyz = (float*)d_out;                    // [8,3,1024]
  float* out2 = (float*)d_out + B_ * 3 * M_;      // [8,128,1024]

  const size_t nidx_bytes = (size_t)B_ * M_ * K_ * sizeof(int);        // 2 MB
  const size_t ft_bytes = (size_t)B_ * N_ * FTW * sizeof(float);       // ~17.8 MB
  int* nidx = (int*)d_ws;
  float* ft = (float*)((char*)d_ws + nidx_bytes);
  const bool use_ft = ws_size >= nidx_bytes + ft_bytes;

  // FPS (blocks 0-7) fused with ft-table build (blocks 8-63) — independent work.
  hipLaunchKernelGGL(fps_ft_kernel, dim3(use_ft ? 64 : 8), dim3(256), 0, stream,
                     xyz, feat, ft, nxyz);
  hipLaunchKernelGGL(ballq_kernel, dim3(B_ * M_ / 4), dim3(256), 0, stream, xyz, nxyz, nidx);
  if (use_ft) {
    hipLaunchKernelGGL((mlp_kernel<true>), dim3(B_ * M_), dim3(64), 0, stream,
                       ft, xyz, feat, nidx, nxyz, w0, s0, b0, w1, s1, b1, w2, s2, b2, out2);
  } else {
    hipLaunchKernelGGL((mlp_kernel<false>), dim3(B_ * M_), dim3(64), 0, stream,
                       ft, xyz, feat, nidx, nxyz, w0, s0, b0, w1, s1, b1, w2, s2, b2, out2);
  }
}

// Round 8
// 1302.541 us; speedup vs baseline: 1.2122x; 1.2122x over previous
//
#include <hip/hip_runtime.h>

// PointNet++ SA module: FPS -> ball query -> group -> SharedMLP(3) -> maxpool
// B=8, N=8192, C_IN=64, M=1024, K=64, RADIUS=0.2, MLP=[64,64,128]

#define B_ 8
#define N_ 8192
#define M_ 1024
#define K_ 64
#define FTW 68  // 3 xyz + 64 feat + 1 pad (row = 272B, 16B aligned)

// ---------------------------------------------------------------------------
// u64-key lexicographic merge via DPP (VALU pipe, no LDS).
// key = (f32bits(val) << 32) | ~idx ; distances >= 0 so f32 bits order as u32.
// max(key) == (val desc, idx asc) — associative, any mixing schedule valid.
// ---------------------------------------------------------------------------
template <int CTRL>
__device__ __forceinline__ unsigned long long dpp_key(unsigned long long k) {
  int lo = __builtin_amdgcn_update_dpp(0, (int)(unsigned int)k, CTRL, 0xF, 0xF, true);
  int hi = __builtin_amdgcn_update_dpp(0, (int)(unsigned int)(k >> 32), CTRL, 0xF, 0xF, true);
  unsigned long long o = ((unsigned long long)(unsigned int)hi << 32) | (unsigned int)lo;
  return o > k ? o : k;
}

// 6-level DPP max (pure VALU). Valid global result in lane 63.
// Safe for values >= 0 (bcast zero-fill merges 0.f).
template <int CTRL>
__device__ __forceinline__ float dpp_fmax(float v) {
  int o = __builtin_amdgcn_update_dpp(0, __float_as_int(v), CTRL, 0xF, 0xF, true);
  return fmaxf(v, __int_as_float(o));
}
__device__ __forceinline__ float wave_fmax63(float v) {
  v = dpp_fmax<0xB1>(v);   // quad_perm xor1
  v = dpp_fmax<0x4E>(v);   // quad_perm xor2
  v = dpp_fmax<0x141>(v);  // row_half_mirror
  v = dpp_fmax<0x140>(v);  // row_mirror -> row max in all 16 lanes
  v = dpp_fmax<0x142>(v);  // row_bcast15
  v = dpp_fmax<0x143>(v);  // row_bcast31 -> lane 63 = wave max
  return v;
}

// ---------------------------------------------------------------------------
// Kernel 1 (fused): blocks 0..7 = exact FPS (one CU per batch);
//                   blocks 8..  = build ft[b][n][0..67] = {x,y,z,f0..f63,0}.
// FPS: 256 threads (4 waves, 1/SIMD) x 32 points, R4 schedule (best measured):
// ONE barrier per iteration, parity double-buffered candidates; index carried
// in the u64 key so the post-barrier combine is per-thread self-contained.
// Arithmetic identical to reference: unfused f32 sub/mul/add in x,y,z order;
// argmax tie-break = first occurrence (lexicographic val desc, idx asc).
// ---------------------------------------------------------------------------
__global__ __launch_bounds__(256) void fps_ft_kernel(const float* __restrict__ xyz,
                                                     const float* __restrict__ feat,
                                                     float* __restrict__ ft,
                                                     float* __restrict__ nxyz) {
#pragma clang fp contract(off)
  if (blockIdx.x >= 8) {
    // ---- build_ft path (no LDS use, no barriers) ----
    const int nb = gridDim.x - 8;
    const int total = B_ * N_ * FTW;
    for (int idx = (blockIdx.x - 8) * 256 + threadIdx.x; idx < total; idx += nb * 256) {
      int c = idx % FTW;
      int bn = idx / FTW;
      int n = bn & (N_ - 1);
      int b = bn >> 13;
      float v;
      if (c < 3) v = xyz[(b * 3 + c) * N_ + n];
      else if (c < 67) v = feat[(b * 64 + (c - 3)) * N_ + n];
      else v = 0.f;
      ft[idx] = v;
    }
    return;
  }

  // ---- FPS path ----
  __shared__ float4 pts4[N_];                    // 128 KB point table (w unused)
  __shared__ unsigned long long cand[2][16];     // parity-buffered row-winner keys
  __shared__ int scidx[M_];
  const int b = blockIdx.x;
  const int t = threadIdx.x;
  const int lane = t & 63;
  const int wid = t >> 6;  // 0..3
  const float* xb = xyz + b * 3 * N_;

  for (int n = t; n < N_; n += 256) {
    pts4[n] = make_float4(xb[n], xb[N_ + n], xb[2 * N_ + n], 0.f);
  }

  const int base = t * 32;
  float px[32], py[32], pz[32], mind[32];
#pragma unroll
  for (int j = 0; j < 32; ++j) {
    px[j] = xb[base + j];
    py[j] = xb[N_ + base + j];
    pz[j] = xb[2 * N_ + base + j];
    mind[j] = 1e10f;
  }
  float xl = xb[0], yl = xb[N_], zl = xb[2 * N_];
  if (t == 0) scidx[0] = 0;
  __syncthreads();

  for (int i = 1; i < M_; ++i) {
    float bestv = -1.f;
    int bl = 0;  // local index 0..31 (inline-const cndmask)
#pragma unroll
    for (int j = 0; j < 32; ++j) {
      float dx = __fsub_rn(px[j], xl);
      float dy = __fsub_rn(py[j], yl);
      float dz = __fsub_rn(pz[j], zl);
      float d = __fadd_rn(__fadd_rn(__fmul_rn(dx, dx), __fmul_rn(dy, dy)), __fmul_rn(dz, dz));
      float md = fminf(mind[j], d);
      mind[j] = md;
      if (md > bestv) { bestv = md; bl = j; }  // ascending j -> first max kept
    }
    unsigned long long key =
        ((unsigned long long)__float_as_uint(bestv) << 32) | (unsigned int)(~(base + bl));
    // in-wave reduce to 16-lane-row winners: 4 DPP levels, VALU pipe only
    key = dpp_key<0xB1>(key);   // quad_perm [1,0,3,2]
    key = dpp_key<0x4E>(key);   // quad_perm [2,3,0,1]
    key = dpp_key<0x141>(key);  // row_half_mirror
    key = dpp_key<0x140>(key);  // row_mirror -> 16-lane-row winner
    if ((lane & 15) == 0) cand[i & 1][wid * 4 + (lane >> 4)] = key;
    __syncthreads();
    // combine 16 row winners: broadcast read, 4 DPP levels within each 16-row
    unsigned long long gk = cand[i & 1][lane & 15];
    gk = dpp_key<0xB1>(gk);
    gk = dpp_key<0x4E>(gk);
    gk = dpp_key<0x141>(gk);
    gk = dpp_key<0x140>(gk);
    const int gi = (int)(~(unsigned int)gk);
    if (t == 0) scidx[i] = gi;
    float4 cc = pts4[gi];  // broadcast ds_read_b128, conflict-free
    xl = cc.x; yl = cc.y; zl = cc.z;
    // no second barrier: next iteration's leader writes go to the other parity
  }
  __syncthreads();
  for (int q = t; q < M_; q += 256) {
    int ci = scidx[q];
    float4 c = pts4[ci];
    nxyz[b * 3 * M_ + q] = c.x;
    nxyz[b * 3 * M_ + M_ + q] = c.y;
    nxyz[b * 3 * M_ + 2 * M_ + q] = c.z;
  }
}

// ---------------------------------------------------------------------------
// Kernel 2: ball query — one wave per centroid, ordered first-K within radius.
// Replicates the reference's expanded-form distance exactly (unfused f32).
// Threshold 0.04f == f32(0.2*0.2 computed in python f64).
// ---------------------------------------------------------------------------
__global__ __launch_bounds__(256) void ballq_kernel(const float* __restrict__ xyz,
                                                    const float* __restrict__ nxyz,
                                                    int* __restrict__ nidx) {
  const int lane = threadIdx.x & 63;
  const int g = blockIdx.x * 4 + (threadIdx.x >> 6);  // 0..8191 centroid id
  const int b = g >> 10;
  const int m = g & (M_ - 1);
  const float* xb = xyz + b * 3 * N_;
  const float cx = nxyz[b * 3 * M_ + m];
  const float cy = nxyz[b * 3 * M_ + M_ + m];
  const float cz = nxyz[b * 3 * M_ + 2 * M_ + m];
  const float nc = __fadd_rn(__fadd_rn(__fmul_rn(cx, cx), __fmul_rn(cy, cy)), __fmul_rn(cz, cz));
  int cnt = 0;
  int first = 0;
  int* slot = nidx + (g << 6);
  for (int basei = 0; basei < N_ && cnt < K_; basei += 64) {
    const int n = basei + lane;
    float p_x = xb[n], p_y = xb[N_ + n], p_z = xb[2 * N_ + n];
    float pn = __fadd_rn(__fadd_rn(__fmul_rn(p_x, p_x), __fmul_rn(p_y, p_y)), __fmul_rn(p_z, p_z));
    float dt = __fadd_rn(__fadd_rn(__fmul_rn(cx, p_x), __fmul_rn(cy, p_y)), __fmul_rn(cz, p_z));
    float d2 = __fsub_rn(__fadd_rn(nc, pn), __fmul_rn(2.f, dt));
    bool inr = d2 < 0.04f;
    unsigned long long mk = __ballot(inr);
    if (cnt == 0 && mk != 0ull) first = basei + (__ffsll((long long)mk) - 1);
    int pos = cnt + (int)__popcll(mk & ((1ull << lane) - 1ull));
    if (inr && pos < K_) slot[pos] = n;
    cnt += (int)__popcll(mk);
  }
  if (cnt > K_) cnt = K_;
  if (lane >= cnt) slot[lane] = first;  // pad with first hit (0 if none)
}

// ---------------------------------------------------------------------------
// Kernel 3: fused group + SharedMLP(67->64->64->128) + max over K.
// One wave per (b,m); lane = neighbor column. 4-way output unroll (4
// independent fmaf chains). OCCUPANCY FIX: bridge LDS halved to 64x33 floats
// (8.4KB -> ~19 blocks/CU vs 9) by running layers 0/1 in two 32-output
// phases; __launch_bounds__(64,5) caps VGPRs ~102 (structure needs ~90) so
// LDS, not registers, sets residency (~4.75 waves/SIMD). Stride 33 words is
// bank-conflict-free ((33*lane) mod 32 == lane). Max-pool over the 64
// neighbor lanes stays on the VALU via 6-level DPP chain + readlane.
// Per-output FMA order identical to reference accumulation order.
// ---------------------------------------------------------------------------
template <bool USE_FT>
__global__ __launch_bounds__(64, 5) void mlp_kernel(
    const float* __restrict__ ft, const float* __restrict__ xyz, const float* __restrict__ feat,
    const int* __restrict__ nidx, const float* __restrict__ nxyz,
    const float* __restrict__ w0, const float* __restrict__ s0, const float* __restrict__ b0,
    const float* __restrict__ w1, const float* __restrict__ s1, const float* __restrict__ b1,
    const float* __restrict__ w2, const float* __restrict__ s2, const float* __restrict__ b2,
    float* __restrict__ out2) {
  __shared__ float ylds[64 * 33];  // 8448 B: half-bridge, two 32-out phases
  const int g = blockIdx.x;
  const int b = g >> 10;
  const int m = g & (M_ - 1);
  const int lane = threadIdx.x;
  const int n = nidx[(g << 6) + lane];
  const float cx = nxyz[b * 3 * M_ + m];
  const float cy = nxyz[b * 3 * M_ + M_ + m];
  const float cz = nxyz[b * 3 * M_ + 2 * M_ + m];

  float x0[67];
  if (USE_FT) {
    const float4* row = (const float4*)(ft + (size_t)((b << 13) + n) * FTW);
    float f[FTW];
#pragma unroll
    for (int q = 0; q < 17; ++q) {
      float4 v = row[q];
      f[q * 4 + 0] = v.x; f[q * 4 + 1] = v.y; f[q * 4 + 2] = v.z; f[q * 4 + 3] = v.w;
    }
    x0[0] = f[0] - cx; x0[1] = f[1] - cy; x0[2] = f[2] - cz;
#pragma unroll
    for (int c = 3; c < 67; ++c) x0[c] = f[c];
  } else {
    const float* xb = xyz + b * 3 * N_;
    x0[0] = xb[n] - cx; x0[1] = xb[N_ + n] - cy; x0[2] = xb[2 * N_ + n] - cz;
#pragma unroll
    for (int c = 0; c < 64; ++c) x0[3 + c] = feat[((b << 6) + c) * N_ + n];
  }

  float x1[64];
  // Layer 0: 67 -> 64 in two 32-output phases through the half-bridge
#pragma unroll
  for (int h = 0; h < 2; ++h) {
    for (int oo = 0; oo < 32; oo += 4) {
      const int o = h * 32 + oo;
      const float* wr = w0 + o * 67;
      float a0 = 0.f, a1 = 0.f, a2 = 0.f, a3 = 0.f;
#pragma unroll
      for (int ci = 0; ci < 67; ++ci) {
        float xvv = x0[ci];
        a0 = fmaf(wr[ci], xvv, a0);
        a1 = fmaf(wr[67 + ci], xvv, a1);
        a2 = fmaf(wr[134 + ci], xvv, a2);
        a3 = fmaf(wr[201 + ci], xvv, a3);
      }
      ylds[lane * 33 + oo + 0] = fmaxf(fmaf(a0, s0[o + 0], b0[o + 0]), 0.f);
      ylds[lane * 33 + oo + 1] = fmaxf(fmaf(a1, s0[o + 1], b0[o + 1]), 0.f);
      ylds[lane * 33 + oo + 2] = fmaxf(fmaf(a2, s0[o + 2], b0[o + 2]), 0.f);
      ylds[lane * 33 + oo + 3] = fmaxf(fmaf(a3, s0[o + 3], b0[o + 3]), 0.f);
    }
#pragma unroll
    for (int c = 0; c < 32; ++c) x1[h * 32 + c] = ylds[lane * 33 + c];
  }

  float x2[64];
  // Layer 1: 64 -> 64 in two 32-output phases
#pragma unroll
  for (int h = 0; h < 2; ++h) {
    for (int oo = 0; oo < 32; oo += 4) {
      const int o = h * 32 + oo;
      const float* wr = w1 + o * 64;
      float a0 = 0.f, a1 = 0.f, a2 = 0.f, a3 = 0.f;
#pragma unroll
      for (int ci = 0; ci < 64; ++ci) {
        float xvv = x1[ci];
        a0 = fmaf(wr[ci], xvv, a0);
        a1 = fmaf(wr[64 + ci], xvv, a1);
        a2 = fmaf(wr[128 + ci], xvv, a2);
        a3 = fmaf(wr[192 + ci], xvv, a3);
      }
      ylds[lane * 33 + oo + 0] = fmaxf(fmaf(a0, s1[o + 0], b1[o + 0]), 0.f);
      ylds[lane * 33 + oo + 1] = fmaxf(fmaf(a1, s1[o + 1], b1[o + 1]), 0.f);
      ylds[lane * 33 + oo + 2] = fmaxf(fmaf(a2, s1[o + 2], b1[o + 2]), 0.f);
      ylds[lane * 33 + oo + 3] = fmaxf(fmaf(a3, s1[o + 3], b1[o + 3]), 0.f);
    }
#pragma unroll
    for (int c = 0; c < 32; ++c) x2[h * 32 + c] = ylds[lane * 33 + c];
  }

  // Layer 2: 64 -> 128, fused max over K (4 outputs in flight, DPP reduce)
  float* outbm = out2 + (size_t)(b * 128) * M_ + m;
  for (int o = 0; o < 128; o += 4) {
    const float* wr = w2 + o * 64;
    float a0 = 0.f, a1 = 0.f, a2 = 0.f, a3 = 0.f;
#pragma unroll
    for (int ci = 0; ci < 64; ++ci) {
      float xvv = x2[ci];
      a0 = fmaf(wr[ci], xvv, a0);
      a1 = fmaf(wr[64 + ci], xvv, a1);
      a2 = fmaf(wr[128 + ci], xvv, a2);
      a3 = fmaf(wr[192 + ci], xvv, a3);
    }
    float v0 = fmaxf(fmaf(a0, s2[o + 0], b2[o + 0]), 0.f);
    float v1 = fmaxf(fmaf(a1, s2[o + 1], b2[o + 1]), 0.f);
    float v2 = fmaxf(fmaf(a2, s2[o + 2], b2[o + 2]), 0.f);
    float v3 = fmaxf(fmaf(a3, s2[o + 3], b2[o + 3]), 0.f);
    v0 = wave_fmax63(v0);
    v1 = wave_fmax63(v1);
    v2 = wave_fmax63(v2);
    v3 = wave_fmax63(v3);
    float g0 = __int_as_float(__builtin_amdgcn_readlane(__float_as_int(v0), 63));
    float g1 = __int_as_float(__builtin_amdgcn_readlane(__float_as_int(v1), 63));
    float g2 = __int_as_float(__builtin_amdgcn_readlane(__float_as_int(v2), 63));
    float g3 = __int_as_float(__builtin_amdgcn_readlane(__float_as_int(v3), 63));
    if (lane == ((o + 0) & 63)) outbm[(o + 0) * M_] = g0;
    if (lane == ((o + 1) & 63)) outbm[(o + 1) * M_] = g1;
    if (lane == ((o + 2) & 63)) outbm[(o + 2) * M_] = g2;
    if (lane == ((o + 3) & 63)) outbm[(o + 3) * M_] = g3;
  }
}

// ---------------------------------------------------------------------------
extern "C" void kernel_launch(void* const* d_in, const int* in_sizes, int n_in,
                              void* d_out, int out_size, void* d_ws, size_t ws_size,
                              hipStream_t stream) {
  const float* xyz = (const float*)d_in[0];
  const float* feat = (const float*)d_in[1];
  const float* w0 = (const float*)d_in[2];
  const float* s0 = (const float*)d_in[3];
  const float* b0 = (const float*)d_in[4];
  const float* w1 = (const float*)d_in[5];
  const float* s1 = (const float*)d_in[6];
  const float* b1 = (const float*)d_in[7];
  const float* w2 = (const float*)d_in[8];
  const float* s2 = (const float*)d_in[9];
  const float* b2 = (const float*)d_in[10];

  float* nxyz = (float*)d_out;                    // [8,3,1024]
  float* out2 = (float*)d_out + B_ * 3 * M_;      // [8,128,1024]

  const size_t nidx_bytes = (size_t)B_ * M_ * K_ * sizeof(int);        // 2 MB
  const size_t ft_bytes = (size_t)B_ * N_ * FTW * sizeof(float);       // ~17.8 MB
  int* nidx = (int*)d_ws;
  float* ft = (float*)((char*)d_ws + nidx_bytes);
  const bool use_ft = ws_size >= nidx_bytes + ft_bytes;

  // FPS (blocks 0-7) fused with ft-table build (blocks 8-63) — independent work.
  hipLaunchKernelGGL(fps_ft_kernel, dim3(use_ft ? 64 : 8), dim3(256), 0, stream,
                     xyz, feat, ft, nxyz);
  hipLaunchKernelGGL(ballq_kernel, dim3(B_ * M_ / 4), dim3(256), 0, stream, xyz, nxyz, nidx);
  if (use_ft) {
    hipLaunchKernelGGL((mlp_kernel<true>), dim3(B_ * M_), dim3(64), 0, stream,
                       ft, xyz, feat, nidx, nxyz, w0, s0, b0, w1, s1, b1, w2, s2, b2, out2);
  } else {
    hipLaunchKernelGGL((mlp_kernel<false>), dim3(B_ * M_), dim3(64), 0, stream,
                       ft, xyz, feat, nidx, nxyz, w0, s0, b0, w1, s1, b1, w2, s2, b2, out2);
  }
}